// Round 1
// baseline (105.397 us; speedup 1.0000x reference)
//
#include <hip/hip_runtime.h>

// LambdaRankLoss: B=64, N=1024, binary relevances, SIGMA=1, NDCG@10, EPS=1e-8.
// loss = (1/num_pairs) * sum_{valid b} sum_{i in rel, j in nonrel}
//            |disc_i - disc_j| / (idcg_b + eps) * softplus(s_j - s_i)
// valid b  <=>  0 < nrel_b < N  (binary gains => idcg>0 iff nrel>0)
// idcg_b = sum_{p < min(nrel_b,10)} 1/log2(p+2)

#define NPOS  1024
#define SPLIT 4        // blocks per batch; grid = B*SPLIT
#define KTOP  10
#define EPSF  1e-8f
#define MAXB  64

// log(1 + exp(z)), numerically stable, fast-path transcendentals.
// Tolerance is ~2% relative so __expf/__logf are plenty accurate.
__device__ __forceinline__ float softplus_f(float z) {
    float a = fabsf(z);
    return fmaxf(z, 0.0f) + __logf(1.0f + __expf(-a));
}

__global__ __launch_bounds__(256) void lr_pair_kernel(
    const float* __restrict__ scores,
    const int*   __restrict__ relev,
    double*      __restrict__ partials)
{
    __shared__ float rs[NPOS], rd[NPOS];   // rel:    score, discount
    __shared__ float ns[NPOS], nd[NPOS];   // nonrel: score, discount
    __shared__ int   nrel_s, nnon_s;
    __shared__ double wsum[4];

    const int b     = blockIdx.x / SPLIT;
    const int slice = blockIdx.x % SPLIT;
    const int tid   = threadIdx.x;

    if (tid == 0) { nrel_s = 0; nnon_s = 0; }
    __syncthreads();

    const float* srow = scores + (size_t)b * NPOS;
    const int*   rrow = relev  + (size_t)b * NPOS;

    // Stage this batch into rel / nonrel LDS lists (append order irrelevant).
    for (int idx = tid; idx < NPOS; idx += 256) {
        float s = srow[idx];
        float d = 1.0f / log2f((float)idx + 2.0f);  // position discount
        if (rrow[idx] > 0) {
            int p = atomicAdd(&nrel_s, 1);
            rs[p] = s; rd[p] = d;
        } else {
            int p = atomicAdd(&nnon_s, 1);
            ns[p] = s; nd[p] = d;
        }
    }
    __syncthreads();

    const int nrel = nrel_s, nnon = nnon_s;

    double block_total = 0.0;
    if (nrel > 0 && nnon > 0) {
        float idcg = 0.0f;
        const int kk = min(nrel, KTOP);
        for (int p = 0; p < kk; ++p) idcg += 1.0f / log2f((float)p + 2.0f);
        const float inv_idcg = 1.0f / (idcg + EPSF);

        const int i0 = (slice * nrel) / SPLIT;
        const int i1 = ((slice + 1) * nrel) / SPLIT;

        float acc = 0.0f;  // ~256 small terms per thread: fp32 is fine
        for (int i = i0; i < i1; ++i) {
            const float si = rs[i];   // wave-uniform LDS broadcast
            const float di = rd[i];
            for (int j = tid; j < nnon; j += 256) {
                float z     = ns[j] - si;                    // -(s_i - s_j)
                float delta = fabsf(di - nd[j]) * inv_idcg;
                acc += delta * softplus_f(z);
            }
        }

        // wave(64) shuffle reduce, then cross-wave via LDS in double
        float v = acc;
        #pragma unroll
        for (int off = 32; off >= 1; off >>= 1) v += __shfl_down(v, off);
        const int lane = tid & 63, wave = tid >> 6;
        if (lane == 0) wsum[wave] = (double)v;
        __syncthreads();
        if (tid == 0) block_total = wsum[0] + wsum[1] + wsum[2] + wsum[3];
    }

    if (tid == 0) partials[blockIdx.x] = block_total;
}

__global__ __launch_bounds__(256) void lr_final_kernel(
    const int*    __restrict__ relev,
    const double* __restrict__ partials,
    float*        __restrict__ out,
    int B, int nparts)
{
    __shared__ int    cnt[MAXB];
    __shared__ long long psh[4];
    __shared__ double    dsh[4];

    const int tid = threadIdx.x;
    if (tid < MAXB) cnt[tid] = 0;
    __syncthreads();

    // 4 threads per batch count relevant items
    const int b = tid >> 2, part = tid & 3;
    if (b < B) {
        const int* rrow = relev + (size_t)b * NPOS;
        int c = 0;
        for (int k = part; k < NPOS; k += 4) c += (rrow[k] > 0) ? 1 : 0;
        atomicAdd(&cnt[b], c);
    }
    __syncthreads();

    // num_pairs = sum over valid batches of nrel*(N-nrel)
    long long pairs = 0;
    if (tid < B) {
        int c = cnt[tid];
        if (c > 0 && c < NPOS) pairs = (long long)c * (NPOS - c);
    }
    // sum of double partials (one per thread; nparts <= 256)
    double tot = (tid < nparts) ? partials[tid] : 0.0;

    #pragma unroll
    for (int off = 32; off >= 1; off >>= 1) {
        pairs += __shfl_down(pairs, off);
        tot   += __shfl_down(tot, off);
    }
    const int lane = tid & 63, wave = tid >> 6;
    if (lane == 0) { psh[wave] = pairs; dsh[wave] = tot; }
    __syncthreads();

    if (tid == 0) {
        long long np = psh[0] + psh[1] + psh[2] + psh[3];
        double    tt = dsh[0] + dsh[1] + dsh[2] + dsh[3];
        out[0] = (np > 0) ? (float)(tt / (double)np) : 0.0f;
    }
}

extern "C" void kernel_launch(void* const* d_in, const int* in_sizes, int n_in,
                              void* d_out, int out_size, void* d_ws, size_t ws_size,
                              hipStream_t stream) {
    const float* scores = (const float*)d_in[0];
    const int*   relev  = (const int*)d_in[1];
    float*       out    = (float*)d_out;

    const int B = in_sizes[0] / NPOS;       // 64
    const int nparts = B * SPLIT;           // 256
    double* partials = (double*)d_ws;       // nparts*8 bytes, every slot written

    lr_pair_kernel<<<nparts, 256, 0, stream>>>(scores, relev, partials);
    lr_final_kernel<<<1, 256, 0, stream>>>(relev, partials, out, B, nparts);
}

// Round 3
// 76.139 us; speedup vs baseline: 1.3843x; 1.3843x over previous
//
#include <hip/hip_runtime.h>

// LambdaRankLoss: B=64, N=1024, binary relevances, SIGMA=1, NDCG@10, EPS=1e-8.
// loss = (1/num_pairs) * sum_{valid b} sum_{i in rel, j in nonrel}
//            |disc_i - disc_j| / (idcg_b + eps) * softplus(s_j - s_i)
// valid b  <=>  0 < nrel_b < N ; idcg_b = sum_{p < min(nrel_b,10)} 1/log2(p+2)
//
// DETERMINISM: staging is a stable partition (ballot + chunk-count scan, no
// atomics) so every slice-block of a batch builds the SAME list; slice ranges
// then tile the rel items exactly once. All reductions are fixed-order; each
// block writes its own ws slot; a tiny 2nd kernel does the final reduce.

#define NPOS  1024
#define SPLIT 16       // blocks per batch; grid = B*SPLIT = 1024
#define KTOP  10
#define EPSF  1e-8f
#define NCHUNK (NPOS / 64)   // 16 chunks of one wave each

__device__ __forceinline__ float softplus_f(float z) {
    // log1p(exp(z)) stable: max(z,0) + log(1+exp(-|z|)); ~2% tolerance -> fast path
    return fmaxf(z, 0.0f) + __logf(1.0f + __expf(-fabsf(z)));
}

__global__ __launch_bounds__(256) void lr_pair_kernel(
    const float* __restrict__ scores,
    const int*   __restrict__ relev,
    double*      __restrict__ partials,
    unsigned int* __restrict__ pairCnt)
{
    __shared__ float2 rel2[NPOS];    // (score, disc*inv_idcg), stable order
    __shared__ float2 non2[NPOS];
    __shared__ int    cnt[NCHUNK];   // rel count per 64-item chunk
    __shared__ double wsum[4];

    const int b     = blockIdx.x / SPLIT;
    const int slice = blockIdx.x % SPLIT;
    const int tid   = threadIdx.x;
    const int lane  = tid & 63;
    const int wave  = tid >> 6;

    const float* srow = scores + (size_t)b * NPOS;
    const int*   rrow = relev  + (size_t)b * NPOS;

    // ---- Phase 1: load + per-chunk ballot counts (chunk c -> wave c&3) ----
    float sv[4], dv[4];
    int   rposv[4];
    bool  rf[4];
    #pragma unroll
    for (int it = 0; it < 4; ++it) {
        const int c   = it * 4 + wave;
        const int idx = c * 64 + lane;
        sv[it] = srow[idx];
        dv[it] = 1.0f / log2f((float)idx + 2.0f);
        const bool r = rrow[idx] > 0;
        rf[it] = r;
        unsigned long long m = __ballot(r);
        rposv[it] = __popcll(m & ((1ull << lane) - 1ull));
        if (lane == 0) cnt[c] = __popcll(m);
    }
    __syncthreads();

    // ---- Phase 2: deterministic stable scatter (base = scan of cnt[]) ----
    #pragma unroll
    for (int it = 0; it < 4; ++it) {
        const int c = it * 4 + wave;
        int rbase = 0;
        for (int cc = 0; cc < c; ++cc) rbase += cnt[cc];   // LDS broadcast reads
        const int nbase = c * 64 - rbase;
        if (rf[it]) rel2[rbase + rposv[it]]          = make_float2(sv[it], dv[it]);
        else        non2[nbase + (lane - rposv[it])] = make_float2(sv[it], dv[it]);
    }
    __syncthreads();

    int nrel = 0;
    #pragma unroll
    for (int c = 0; c < NCHUNK; ++c) nrel += cnt[c];
    const int nnon = NPOS - nrel;

    double block_total = 0.0;
    if (nrel > 0 && nnon > 0) {
        float idcg = 0.0f;
        const int kk = min(nrel, KTOP);
        for (int p = 0; p < kk; ++p) idcg += 1.0f / log2f((float)p + 2.0f);
        const float inv_idcg = 1.0f / (idcg + EPSF);

        // pre-scale discounts so delta = |da - db| directly (deterministic)
        for (int k = tid; k < nrel; k += 256) rel2[k].y *= inv_idcg;
        for (int k = tid; k < nnon; k += 256) non2[k].y *= inv_idcg;
        __syncthreads();

        const int i0 = (slice * nrel) / SPLIT;
        const int i1 = ((slice + 1) * nrel) / SPLIT;

        float acc = 0.0f;   // <=~64 terms/thread at SPLIT=16: fp32 fine
        int i = i0;
        for (; i + 4 <= i1; i += 4) {
            const float2 a0 = rel2[i], a1 = rel2[i+1], a2 = rel2[i+2], a3 = rel2[i+3];
            for (int j = tid; j < nnon; j += 256) {
                const float2 bj = non2[j];            // one ds_read_b64 / 4 pairs
                acc += fabsf(a0.y - bj.y) * softplus_f(bj.x - a0.x);
                acc += fabsf(a1.y - bj.y) * softplus_f(bj.x - a1.x);
                acc += fabsf(a2.y - bj.y) * softplus_f(bj.x - a2.x);
                acc += fabsf(a3.y - bj.y) * softplus_f(bj.x - a3.x);
            }
        }
        for (; i < i1; ++i) {
            const float2 a0 = rel2[i];
            for (int j = tid; j < nnon; j += 256) {
                const float2 bj = non2[j];
                acc += fabsf(a0.y - bj.y) * softplus_f(bj.x - a0.x);
            }
        }

        // fixed-order wave shuffle reduce -> cross-wave LDS in double
        #pragma unroll
        for (int off = 32; off >= 1; off >>= 1) acc += __shfl_down(acc, off);
        if (lane == 0) wsum[wave] = (double)acc;
        __syncthreads();
        if (tid == 0) block_total = wsum[0] + wsum[1] + wsum[2] + wsum[3];
    }

    if (tid == 0) {
        partials[blockIdx.x] = block_total;                 // own slot, no race
        if (slice == 0)
            pairCnt[b] = (nrel > 0 && nnon > 0) ? (unsigned int)(nrel * nnon) : 0u;
    }
}

__global__ __launch_bounds__(256) void lr_final_kernel(
    const double*       __restrict__ partials,
    const unsigned int* __restrict__ pairCnt,
    float*              __restrict__ out,
    int B, int nparts)
{
    __shared__ double    dsh[4];
    __shared__ long long psh[4];

    const int tid = threadIdx.x, lane = tid & 63, wave = tid >> 6;

    // fixed-order per-thread partial sums (nparts = 1024 = 4*256)
    double tot = 0.0;
    for (int k = tid; k < nparts; k += 256) tot += partials[k];
    long long pairs = (tid < B) ? (long long)pairCnt[tid] : 0;

    #pragma unroll
    for (int off = 32; off >= 1; off >>= 1) {
        tot   += __shfl_down(tot, off);
        pairs += __shfl_down(pairs, off);
    }
    if (lane == 0) { dsh[wave] = tot; psh[wave] = pairs; }
    __syncthreads();
    if (tid == 0) {
        double    tt = dsh[0] + dsh[1] + dsh[2] + dsh[3];
        long long np = psh[0] + psh[1] + psh[2] + psh[3];
        out[0] = (np > 0) ? (float)(tt / (double)np) : 0.0f;
    }
}

extern "C" void kernel_launch(void* const* d_in, const int* in_sizes, int n_in,
                              void* d_out, int out_size, void* d_ws, size_t ws_size,
                              hipStream_t stream) {
    const float* scores = (const float*)d_in[0];
    const int*   relev  = (const int*)d_in[1];
    float*       out    = (float*)d_out;
    const int    B      = in_sizes[0] / NPOS;   // 64
    const int    nparts = B * SPLIT;            // 1024

    double*       partials = (double*)d_ws;                 // nparts doubles
    unsigned int* pairCnt  = (unsigned int*)(partials + nparts);  // B uints
    // every slot of partials/pairCnt is written by lr_pair_kernel: no memset

    lr_pair_kernel<<<nparts, 256, 0, stream>>>(scores, relev, partials, pairCnt);
    lr_final_kernel<<<1, 256, 0, stream>>>(partials, pairCnt, out, B, nparts);
}